// Round 2
// baseline (344.016 us; speedup 1.0000x reference)
//
#include <hip/hip_runtime.h>

#define NC 32
#define NVOX (96*96*96)
#define NB 512            // blocks per sample; 2*NB = 1024 = exactly 4 blocks/CU
#define TPB 256

// per-block workspace slot layout (floats)
#define WS_CE     0
#define WS_SP     32
#define WS_SPT    64
#define WS_SINKI  96
#define WS_SIB    100
#define WS_TGT    104
#define WS_HIST   128
#define SLOT_STRIDE 1152          // 128 + 1024
#define NSLOT     (2 * NB)        // 1024
#define FINAL_OFF (NSLOT * SLOT_STRIDE)
// completion counter lives INSIDE slot 0's dead field range (108..127 unused by
// finalize); keeps total ws footprint identical to the proven-passing kernel.
#define CTR_IDX   124
#define NCHUNK    8
#define BLK_PER_CH (NB / NCHUNK)  // 64
#define RED_BLK_X ((2 * SLOT_STRIDE + TPB - 1) / TPB)   // 9 (9*256 == 2304 exactly)
#define RED_NBLK  (RED_BLK_X * NCHUNK)                  // 72

__device__ __forceinline__ float wave_reduce(float v) {
    #pragma unroll
    for (int off = 32; off > 0; off >>= 1)
        v += __shfl_down(v, off, 64);
    return v;
}

// e^x lives in 32 registers (all indexing static via full unroll). The 3
// dynamically-indexed probabilities are produced by select chains (ysafe/pyi
// known before the sweep) and by latching the group's sink value inside the
// argmax chain (sink = first channel of each group).
__global__ __launch_bounds__(TPB, 4) void voxel_kernel(
    const float* __restrict__ images,
    const int*   __restrict__ targets,
    const int*   __restrict__ masks,     // bools promoted to 4-byte on device
    float* __restrict__ ws,
    float* __restrict__ pred_out)
{
    const int slot = blockIdx.x;
    const int b    = slot & 1;          // interleave samples across XCDs
    const int blk  = slot >> 1;
    const int tid  = threadIdx.x;

    __shared__ float s_hist[NC * NC];
    __shared__ float s_spt[NC];
    __shared__ float s_mf[NC];
    __shared__ float s_red[45];         // ce, sp[32], sinkI[4], sib[4], tgt[4]

    for (int i = tid; i < NC * NC; i += TPB) s_hist[i] = 0.f;
    if (tid < 45) s_red[tid] = 0.f;
    if (tid < NC) {
        s_spt[tid] = 0.f;
        s_mf[tid]  = (masks[b * NC + tid] != 0) ? 1.f : 0.f;
    }
    // block 0 zeroes the final accumulator + in-slot counter (replaces the
    // hipMemsetAsync dispatch); reduce_kernel runs strictly after voxel_kernel
    // (same stream), so any-time zeroing here is ordered before its use.
    if (slot == 0) {
        float* wsf = ws + FINAL_OFF;
        for (int i = tid; i < 2 * SLOT_STRIDE; i += TPB) wsf[i] = 0.f;
        if (tid == 0) *(unsigned int*)(ws + CTR_IDX) = 0u;
    }
    __syncthreads();

    const float* img  = images + (size_t)b * NC * NVOX;
    const int*   tgt  = targets + (size_t)b * NVOX;
    float*       pout = pred_out + (size_t)b * NVOX;
    float*       wsb  = ws + (size_t)slot * SLOT_STRIDE;

    float sp[NC];
    #pragma unroll
    for (int c = 0; c < NC; ++c) sp[c] = 0.f;
    float ce = 0.f;
    float sinkI[4] = {0.f, 0.f, 0.f, 0.f};
    float sibc[4]  = {0.f, 0.f, 0.f, 0.f};
    float tgtc[4]  = {0.f, 0.f, 0.f, 0.f};

    for (int v = blk * TPB + tid; v < NVOX; v += NB * TPB) {
        const int  y     = tgt[v];
        const bool valid = (y != 255);
        const int  ysafe = valid ? y : 0;
        const float vwf  = valid ? 1.f : 0.f;
        const int  py    = (ysafe >= 4) ? (ysafe - 4) / 7 : -1; // parent of y or -1
        const int  pyi   = (py >= 0) ? py : 0;

        // single sweep: load -> exp -> register row; online sum + argmax;
        // pick off the two target-indexed values and the sink-of-pred value.
        float ev[NC];
        float sum = 0.f, best = -3.4e38f;
        float pyv_e = 0.f, ppv_e = 0.f, cur = 0.f, esk = 0.f;
        int   pred = 4;
        #pragma unroll
        for (int c = 0; c < NC; ++c) {
            const float x = img[(size_t)c * NVOX + v];
            const float e = __expf(x);
            ev[c] = e;
            sum  += e;
            pyv_e = (c == ysafe) ? e : pyv_e;          // p-numerator of target class
            if (c < 4)                                  // parents are classes 0..3
                ppv_e = (c == pyi) ? e : ppv_e;
            if (c >= 4 && ((c - 4) % 7) == 0)           // group head == sink channel
                cur = e;                                // (static after unroll)
            if (c >= 4) {                               // argmax over leaves, latch sink
                const bool g = (x > best);
                best = g ? x : best;
                pred = g ? c : pred;
                esk  = g ? cur : esk;                   // == ev[4+7*((pred-4)/7)] exactly
            }
        }
        const float rinv = 1.f / sum;
        pout[v] = (float)pred;

        const int pp = (pred - 4) / 7;                  // parent of pred
        const float pyv  = pyv_e * rinv;
        const float ppv  = ppv_e * rinv;
        const float eskv = esk   * rinv;

        // CE
        float term = __logf(fminf(fmaxf(pyv, 1e-7f), 1.f - 1e-7f)) * s_mf[ysafe];
        if (py >= 0)
            term += __logf(fminf(fmaxf(ppv, 1e-7f), 1.f - 1e-7f)) * s_mf[pyi];
        ce -= term * vwf;

        // dice intersection terms
        atomicAdd(&s_spt[ysafe], pyv * vwf);
        if (py >= 0) atomicAdd(&s_spt[pyi], ppv * vwf);

        // joint histogram
        atomicAdd(&s_hist[pred * NC + ysafe], vwf);

        // sink accounting (static k indices; only k==pp can take the tgt branch)
        const bool pm = (s_mf[pred] == 0.f);
        #pragma unroll
        for (int k = 0; k < 4; ++k) {
            const int  sk   = 4 + 7 * k;
            const bool ysib = (py == k) && (ysafe != sk);
            const bool msib = pm && (pp == k) && (pred != sk);
            const bool sib  = ysib || msib;
            if (sib && valid) sibc[k] += 1.f;
            if ((pp == k) && !sib && valid) {
                tgtc[k]  += 1.f;
                sinkI[k] += eskv;
            }
        }

        // per-class prob sums straight from registers (was: 32 LDS reads)
        const float rw = rinv * vwf;
        #pragma unroll
        for (int c = 0; c < NC; ++c)
            sp[c] = __builtin_fmaf(ev[c], rw, sp[c]);
    }

    // wave reduce -> 4 LDS atomics per value -> private slot stores
    const int lane = tid & 63;
    {
        float r = wave_reduce(ce);
        if (lane == 0) atomicAdd(&s_red[0], r);
    }
    #pragma unroll
    for (int c = 0; c < NC; ++c) {
        float r = wave_reduce(sp[c]);
        if (lane == 0) atomicAdd(&s_red[1 + c], r);
    }
    #pragma unroll
    for (int k = 0; k < 4; ++k) {
        float r = wave_reduce(sinkI[k]);
        if (lane == 0) atomicAdd(&s_red[33 + k], r);
        r = wave_reduce(sibc[k]);
        if (lane == 0) atomicAdd(&s_red[37 + k], r);
        r = wave_reduce(tgtc[k]);
        if (lane == 0) atomicAdd(&s_red[41 + k], r);
    }
    __syncthreads();

    // plain coalesced stores to this block's private slot — zero global atomics
    for (int i = tid; i < NC * NC; i += TPB) wsb[WS_HIST + i] = s_hist[i];
    if (tid == 0) wsb[WS_CE] = s_red[0];
    if (tid < NC) {
        wsb[WS_SP  + tid] = s_red[1 + tid];
        wsb[WS_SPT + tid] = s_spt[tid];
    }
    if (tid < 4) {
        wsb[WS_SINKI + tid] = s_red[33 + tid];
        wsb[WS_SIB   + tid] = s_red[37 + tid];
        wsb[WS_TGT   + tid] = s_red[41 + tid];
    }
}

// stage A (72 blocks): each block sums a 64-slot chunk for 256 values, one
// atomic each; the LAST block to finish (fence + counter) runs the finalize
// in-place — removes the separate finalize dispatch. Note: the sum loop reads
// the counter float (slot-0 val 124) into wsf[124], a dead field finalize
// never reads — harmless.
__global__ __launch_bounds__(TPB) void reduce_kernel(
    const float* __restrict__ ws,
    float* __restrict__ wsf,
    const int* __restrict__ masks,
    float* __restrict__ out,
    unsigned int* __restrict__ ctr)
{
    const int v = blockIdx.x * TPB + threadIdx.x;   // value id, 0..2303 (exact)
    {
        const int b    = v / SLOT_STRIDE;
        const int val  = v % SLOT_STRIDE;
        const int blk0 = blockIdx.y * BLK_PER_CH;
        const float* base = ws + (size_t)b * SLOT_STRIDE + val;
        float s = 0.f;
        #pragma unroll 8
        for (int i = 0; i < BLK_PER_CH; ++i)
            s += base[(size_t)(2 * (blk0 + i)) * SLOT_STRIDE];
        atomicAdd(&wsf[v], s);
    }

    // last-block-done handshake (release: fence before count; acquire: fence after)
    __shared__ unsigned int s_last;
    __threadfence();
    __syncthreads();
    if (threadIdx.x == 0) s_last = atomicAdd(ctr, 1u);
    __syncthreads();
    if (s_last != RED_NBLK - 1) return;
    __threadfence();

    // ---- finalize (single block; threads 0..63 -> sample 0, 64..127 -> sample 1)
    __shared__ float f_col[2][NC], f_row[2][NC], f_dice[2][NC], f_mf[2][NC];
    const int t  = threadIdx.x & 63;
    const int fb = threadIdx.x >> 6;                // 0..3, only fb<2 active
    const bool act = (fb < 2) && (t < NC);

    if (act) {
        const float* hist = wsf + (size_t)fb * SLOT_STRIDE + WS_HIST;
        float cs = 0.f, rs = 0.f;
        for (int j = 0; j < NC; ++j) {
            cs += hist[j * NC + t];
            rs += hist[t * NC + j];
        }
        f_col[fb][t] = cs;
        f_row[fb][t] = rs;
        f_mf[fb][t]  = (masks[fb * NC + t] != 0) ? 1.f : 0.f;
    }
    __syncthreads();

    if (act) {
        const float* wsb  = wsf + (size_t)fb * SLOT_STRIDE;
        const float* hist = wsb + WS_HIST;
        const int c = t;
        float ycnt, pcnt, tp;
        if (c < 4) {
            int idx[8];
            idx[0] = c;
            for (int j = 0; j < 7; ++j) idx[1 + j] = 4 + 7 * c + j;
            ycnt = f_col[fb][c]; pcnt = f_row[fb][c];
            for (int j = 0; j < 7; ++j) { ycnt += f_col[fb][idx[1 + j]]; pcnt += f_row[fb][idx[1 + j]]; }
            tp = 0.f;
            for (int a = 0; a < 8; ++a)
                for (int d = 0; d < 8; ++d)
                    tp += hist[idx[a] * NC + idx[d]];
        } else {
            ycnt = f_col[fb][c]; pcnt = f_row[fb][c];
            tp = hist[c * NC + c];
        }
        const float mf = f_mf[fb][c];
        out[6 + (fb * NC + c) * 3 + 0] = tp * mf;
        out[6 + (fb * NC + c) * 3 + 1] = (pcnt - tp) * mf;
        out[6 + (fb * NC + c) * 3 + 2] = (ycnt - tp) * mf;
        f_dice[fb][c] = (1.f - 2.f * wsb[WS_SPT + c] / (wsb[WS_SP + c] + ycnt + 1e-5f)) * mf;
    }
    __syncthreads();

    if (fb < 2 && t == 0) {
        const float* wsb = wsf + (size_t)fb * SLOT_STRIDE;
        float vw = 0.f, dsum = 0.f, msum = 0.f;
        for (int c = 0; c < NC; ++c) {
            vw   += f_col[fb][c];
            dsum += f_dice[fb][c];
            msum += f_mf[fb][c];
        }
        const float cel  = wsb[WS_CE] / fmaxf(vw, 1.f);
        const float dice = dsum / fmaxf(msum, 1.f);
        float cnt = 0.f, sd = 0.f;
        for (int k = 0; k < 4; ++k) {
            float fl = (wsb[WS_SIB + k] > 0.f) ? 1.f : 0.f;
            float d  = 1.f - (2.f * wsb[WS_SINKI + k] + 1e-5f) /
                             (wsb[WS_SP + 4 + 7 * k] + wsb[WS_TGT + k] + 1e-5f);
            cnt += fl;
            sd  += d * fl;
        }
        out[fb * 3 + 0] = cel;
        out[fb * 3 + 1] = dice;
        out[fb * 3 + 2] = (cnt > 0.f) ? 0.1f * (sd / fmaxf(cnt, 1.f)) : 0.f;
    }
}

extern "C" void kernel_launch(void* const* d_in, const int* in_sizes, int n_in,
                              void* d_out, int out_size, void* d_ws, size_t ws_size,
                              hipStream_t stream) {
    const float* images  = (const float*)d_in[0];
    const int*   targets = (const int*)d_in[1];
    const int*   masks   = (const int*)d_in[2];
    float* out = (float*)d_out;
    float* ws  = (float*)d_ws;
    float* wsf = ws + FINAL_OFF;

    // out layout: loss (2*3) | cm (2*32*3) | pred (2*96^3) as floats
    // (wsf + counter are zeroed by voxel_kernel block 0 — no memset dispatch)
    voxel_kernel<<<dim3(NSLOT), dim3(TPB), 0, stream>>>(
        images, targets, masks, ws, out + 6 + 2 * NC * 3);
    reduce_kernel<<<dim3(RED_BLK_X, NCHUNK), dim3(TPB), 0, stream>>>(
        ws, wsf, masks, out, (unsigned int*)(ws + CTR_IDX));
}